// Round 15
// baseline (153.175 us; speedup 1.0000x reference)
//
#include <hip/hip_runtime.h>
#include <hip/hip_bf16.h>

typedef unsigned short u16;
typedef unsigned int u32;
typedef __attribute__((ext_vector_type(2))) float f32x2;
typedef __attribute__((ext_vector_type(4))) float f32x4;
typedef __attribute__((ext_vector_type(16))) float f32x16;
typedef __attribute__((ext_vector_type(8))) short short8;
typedef __attribute__((ext_vector_type(4))) u32 u32x4;

#define SEQ 2048
#define FD  1024
#define NH  16
#define DHD 64

// R15 = R14 (known-good, 137.5us) + prep-fold: proj's A-operand reg-stages
// directly from fp32 Q/K/V (load+cvtpk+ds_write), W keeps global_load_lds.
// prep shrinks to the W-cast only. attn/out_proj/epilogues byte-identical to R14.

__device__ __forceinline__ u16 f2bf(float f) {
  __hip_bfloat16 h = __float2bfloat16(f);
  return *reinterpret_cast<u16*>(&h);
}
__device__ __forceinline__ u32 pack2bf(float lo, float hi) {
  return (u32)f2bf(lo) | ((u32)f2bf(hi) << 16);
}
// hardware packed f32->bf16 (RNE), 1 instr for 2 values (T12 recipe)
__device__ __forceinline__ u32 cvtpk(float lo, float hi) {
  u32 r;
  asm("v_cvt_pk_bf16_f32 %0, %1, %2" : "=v"(r) : "v"(lo), "v"(hi));
  return r;
}

// async global->LDS, 16B per lane. LDS dest = wave-uniform base + lane*16.
#define GLOAD_LDS16(gp, lp)                                        \
  __builtin_amdgcn_global_load_lds(                                \
      (const __attribute__((address_space(1))) unsigned int*)(gp), \
      (__attribute__((address_space(3))) unsigned int*)(lp), 16, 0, 0)

// ---- prep: fp32->bf16 cast of Wq,Wk,Wv,Wo only (->Wbf[4]). 4M f32, grid 2048.
__global__ __launch_bounds__(256) void prep_kernel(
    const float* __restrict__ Wq, const float* __restrict__ Wk, const float* __restrict__ Wv,
    const float* __restrict__ Wo, u16* __restrict__ Wbf) {
  const size_t j = ((size_t)blockIdx.x * 256 + threadIdx.x) * 8;
  const int w = (int)(j >> 20);
  const size_t off = j & 0xFFFFF;
  const float* src = (w == 0 ? Wq : w == 1 ? Wk : w == 2 ? Wv : Wo) + off;
  u16* dst = Wbf + j;
  f32x4 a = *reinterpret_cast<const f32x4*>(src);
  f32x4 b = *reinterpret_cast<const f32x4*>(src + 4);
  union { u32 u[4]; short8 s; } pk;
  pk.u[0] = pack2bf(a[0], a[1]); pk.u[1] = pack2bf(a[2], a[3]);
  pk.u[2] = pack2bf(b[0], b[1]); pk.u[3] = pack2bf(b[2], b[3]);
  *reinterpret_cast<short8*>(dst) = pk.s;
}

// ---- m97-structure 128x128 GEMM body: C = A[M,1024] * W[N,1024]^T, both bf16,
// BK=32, global_load_lds(16) staging, 16x16x32 MFMA, fp32 acc[4][4].
__device__ __forceinline__ void gemm128_bf16(const u16* __restrict__ A, const u16* __restrict__ W,
                                             int m0, int n0, u16* As, u16* Bs,
                                             f32x4 (&acc)[4][4]) {
  const int tid = threadIdx.x, lane = tid & 63, wv = tid >> 6;
  const int wr = (tid >> 7) & 1, wc = (tid >> 6) & 1;
  const int lr = lane & 15, lk = (lane >> 4) << 3;
  const int srow = lane >> 2;          // wave-local staging row (0..15)
  const int scol = (lane & 3) << 3;    // staging col (0,8,16,24)
#pragma unroll
  for (int m = 0; m < 4; ++m)
#pragma unroll
    for (int n = 0; n < 4; ++n) acc[m][n] = {0.f, 0.f, 0.f, 0.f};

  for (int k0 = 0; k0 < FD; k0 += 32) {
    __syncthreads();   // previous iteration's ds_reads done (lgkm drain)
#pragma unroll
    for (int c = 0; c < 2; ++c) {
      GLOAD_LDS16(&A[(size_t)(m0 + c * 64 + wv * 16 + srow) * FD + k0 + scol],
                  &As[(c * 64 + wv * 16) * 32]);
      GLOAD_LDS16(&W[(size_t)(n0 + c * 64 + wv * 16 + srow) * FD + k0 + scol],
                  &Bs[(c * 64 + wv * 16) * 32]);
    }
    __syncthreads();   // vmcnt(0) drain: staged tile visible
    short8 a[4], b[4];
#pragma unroll
    for (int m = 0; m < 4; ++m)
      a[m] = *reinterpret_cast<const short8*>(&As[(wr * 64 + m * 16 + lr) * 32 + lk]);
#pragma unroll
    for (int n = 0; n < 4; ++n)
      b[n] = *reinterpret_cast<const short8*>(&Bs[(wc * 64 + n * 16 + lr) * 32 + lk]);
#pragma unroll
    for (int m = 0; m < 4; ++m)
#pragma unroll
      for (int n = 0; n < 4; ++n)
        acc[m][n] = __builtin_amdgcn_mfma_f32_16x16x32_bf16(a[m], b[n], acc[m][n], 0, 0, 0);
  }
}

// ---- mixed-staging variant for proj: A is fp32 (reg-stage + cvtpk + ds_write),
// W is bf16 via global_load_lds. __syncthreads drains vmcnt AND lgkmcnt -> both
// staging paths complete before ds_reads.
__device__ __forceinline__ void gemm128_mixed(const float* __restrict__ A,
                                              const u16* __restrict__ W,
                                              int m0, int n0, u16* As, u16* Bs,
                                              f32x4 (&acc)[4][4]) {
  const int tid = threadIdx.x, lane = tid & 63, wv = tid >> 6;
  const int wr = (tid >> 7) & 1, wc = (tid >> 6) & 1;
  const int lr = lane & 15, lk = (lane >> 4) << 3;
  const int srow = lane >> 2;          // staging row within 16-row band
  const int scol = (lane & 3) << 3;    // staging col (0,8,16,24)
#pragma unroll
  for (int m = 0; m < 4; ++m)
#pragma unroll
    for (int n = 0; n < 4; ++n) acc[m][n] = {0.f, 0.f, 0.f, 0.f};

  for (int k0 = 0; k0 < FD; k0 += 32) {
    __syncthreads();
    // issue async W staging first (B-side, bf16)
#pragma unroll
    for (int c = 0; c < 2; ++c)
      GLOAD_LDS16(&W[(size_t)(n0 + c * 64 + wv * 16 + srow) * FD + k0 + scol],
                  &Bs[(c * 64 + wv * 16) * 32]);
    // A-side: fp32 loads (both halves issued before cvt so latencies overlap)
    f32x4 a0[2], a1[2];
#pragma unroll
    for (int c = 0; c < 2; ++c) {
      const float* s = A + (size_t)(m0 + c * 64 + wv * 16 + srow) * FD + k0 + scol;
      a0[c] = *reinterpret_cast<const f32x4*>(s);
      a1[c] = *reinterpret_cast<const f32x4*>(s + 4);
    }
#pragma unroll
    for (int c = 0; c < 2; ++c) {
      union { u32 u[4]; short8 s8; } pk;
      pk.u[0] = cvtpk(a0[c][0], a0[c][1]); pk.u[1] = cvtpk(a0[c][2], a0[c][3]);
      pk.u[2] = cvtpk(a1[c][0], a1[c][1]); pk.u[3] = cvtpk(a1[c][2], a1[c][3]);
      *reinterpret_cast<short8*>(&As[(c * 64 + wv * 16 + srow) * 32 + scol]) = pk.s8;
    }
    __syncthreads();
    short8 a[4], b[4];
#pragma unroll
    for (int m = 0; m < 4; ++m)
      a[m] = *reinterpret_cast<const short8*>(&As[(wr * 64 + m * 16 + lr) * 32 + lk]);
#pragma unroll
    for (int n = 0; n < 4; ++n)
      b[n] = *reinterpret_cast<const short8*>(&Bs[(wc * 64 + n * 16 + lr) * 32 + lk]);
#pragma unroll
    for (int m = 0; m < 4; ++m)
#pragma unroll
      for (int n = 0; n < 4; ++n)
        acc[m][n] = __builtin_amdgcn_mfma_f32_16x16x32_bf16(a[m], b[n], acc[m][n], 0, 0, 0);
  }
}

// ---- fused QKV projection (A fp32 direct, W bf16) + mask zero-check (bid>=768).
// q -> [B,H,S,DH] (pre-scaled by 0.125*log2e); k,v -> fragment-major K'/V'.
__global__ __launch_bounds__(256) void proj_qkv_kernel(
    const float* __restrict__ Q, const float* __restrict__ K, const float* __restrict__ V,
    const u16* __restrict__ Wbf,
    const float* __restrict__ bq, const float* __restrict__ bk, const float* __restrict__ bv,
    const u32* __restrict__ mask_u32, u32* __restrict__ mflag,
    u16* __restrict__ qh, u16* __restrict__ kh, u16* __restrict__ vF) {
  __shared__ u16 As[128 * 32];
  __shared__ u16 Bs[128 * 32];
  const int bid = blockIdx.x;
  if (bid >= 768) {   // mask zero-check: 2048 blocks x 2048 f32, overlapped with GEMM
    const size_t cb = (size_t)(bid - 768) * 2048 + ((size_t)threadIdx.x << 3);
    u32x4 a = *reinterpret_cast<const u32x4*>(&mask_u32[cb]);
    u32x4 b = *reinterpret_cast<const u32x4*>(&mask_u32[cb + 4]);
    u32 o = a[0] | a[1] | a[2] | a[3] | b[0] | b[1] | b[2] | b[3];
    if (__ballot(o != 0) != 0ull && (threadIdx.x & 63) == 0) atomicOr(mflag, 1u);
    return;
  }
  const int which = bid >> 8;
  const int rr = bid & 255;
  const int slot = rr >> 3;
  const int y = (rr & 7) + 8 * (slot & 3);  // XCD = rr%8 owns 4 m-bands, all n-tiles
  const int x = slot >> 2;
  const int m0 = y * 128, n0 = x * 128;
  const float* A = (which == 0) ? Q : (which == 1) ? K : V;
  const u16* W = Wbf + ((size_t)which << 20);
  const float* bias = (which == 0) ? bq : (which == 1) ? bk : bv;
  const float qscale = 0.18033688011112042f;  // (1/8) * log2(e)

  f32x4 acc[4][4];
  gemm128_mixed(A, W, m0, n0, As, Bs, acc);

  u16* out = (which == 0) ? qh : (which == 1) ? kh : vF;
  const int lane = threadIdx.x & 63;
  const int wr = (threadIdx.x >> 7) & 1, wc = (threadIdx.x >> 6) & 1;
  const int rbase = m0 + wr * 64 + ((lane >> 4) << 2);
  const int cbase = n0 + wc * 64 + (lane & 15);
#pragma unroll
  for (int n = 0; n < 4; ++n) {
    const int col = cbase + n * 16;
    const float bvv = bias[col];
    const int h = col >> 6, dh = col & 63;
#pragma unroll
    for (int m = 0; m < 4; ++m) {
#pragma unroll
      for (int r = 0; r < 4; ++r) {
        const int row = rbase + m * 16 + r;
        const int b = row >> 11, s = row & 2047;
        float v = acc[m][n][r] + bvv;
        if (which == 0) v *= qscale;
        const size_t bhbase = (size_t)(b * 16 + h) * SEQ * DHD;
        size_t idx;
        if (which == 0) {
          idx = bhbase + (size_t)s * 64 + dh;                                   // [B,H,S,DH]
        } else if (which == 1) {
          idx = bhbase + ((size_t)(((s >> 5) * 4 + (dh >> 4)) * 64
                          + ((dh >> 3) & 1) * 32 + (s & 31)) << 3) + (dh & 7);  // K' frag
        } else {
          idx = bhbase + ((size_t)(((s >> 4) * 2 + (dh >> 5)) * 64
                          + ((s >> 3) & 1) * 32 + (dh & 31)) << 3) + (s & 7);   // V' frag
        }
        out[idx] = f2bf(v);
      }
    }
  }
}

__device__ __forceinline__ void load_ktile(const u16* __restrict__ kp, int kv0, int lane,
                                           short8 (&kf)[8]) {
#pragma unroll
  for (int h2 = 0; h2 < 2; ++h2)
#pragma unroll
    for (int d = 0; d < 4; ++d)
      kf[h2 * 4 + d] = *reinterpret_cast<const short8*>(
          &kp[((size_t)((((kv0 >> 5) + h2) * 4 + d) * 64 + lane)) << 3]);
}

#define PV(i) pp[(i) >> 1][(i) & 1]

// one 32q x 64kv tile. p held as f32x2 pairs (all-static idx) so clang emits
// v_pk_{add,fma}_f32 for sum tree / subtract / mask-FMA (halves those VALU ops).
// T13 defer-max (THR=8), T12 cvt_pk pack, T17 max3 triples, T5 setprio.
__device__ __forceinline__ void attn_tile(
    const short8 (&kf)[8], const u16* __restrict__ vp, const float* __restrict__ mrow,
    u32 has_mask, int kv0, int lane, int hi, const short8 (&qf)[4],
    f32x16 (&oacc)[2], float& m2, float& lsum) {
  const float L2E = 1.44269504088896340736f;
  short8 vf[8];
#pragma unroll
  for (int kb = 0; kb < 4; ++kb)
#pragma unroll
    for (int db = 0; db < 2; ++db)
      vf[kb * 2 + db] = *reinterpret_cast<const short8*>(
          &vp[((size_t)((((kv0 >> 4) + kb) * 2 + db) * 64 + lane)) << 3]);

  f32x16 st[2];
  __builtin_amdgcn_s_setprio(1);
#pragma unroll
  for (int h2 = 0; h2 < 2; ++h2) {
    f32x16 z;
#pragma unroll
    for (int e = 0; e < 16; ++e) z[e] = 0.f;
#pragma unroll
    for (int d = 0; d < 4; ++d)
      z = __builtin_amdgcn_mfma_f32_32x32x16_bf16(kf[h2 * 4 + d], qf[d], z, 0, 0, 0);
    st[h2] = z;
  }
  __builtin_amdgcn_s_setprio(0);
  f32x2 pp[16];
  if (__builtin_expect(has_mask != 0, 0)) {
#pragma unroll
    for (int h2 = 0; h2 < 2; ++h2)
#pragma unroll
      for (int g = 0; g < 4; ++g) {
        f32x4 mv = *reinterpret_cast<const f32x4*>(&mrow[kv0 + h2 * 32 + g * 8 + hi * 4]);
        const int pb = h2 * 8 + g * 2;
        f32x2 m0 = {mv[0], mv[1]}, m1 = {mv[2], mv[3]};
        f32x2 s0 = {st[h2][g * 4 + 0], st[h2][g * 4 + 1]};
        f32x2 s1 = {st[h2][g * 4 + 2], st[h2][g * 4 + 3]};
        pp[pb]     = m0 * L2E + s0;   // v_pk_fma_f32
        pp[pb + 1] = m1 * L2E + s1;
      }
  } else {
#pragma unroll
    for (int j = 0; j < 16; ++j)
      pp[j] = {st[j >> 3][(2 * j) & 15], st[j >> 3][(2 * j + 1) & 15]};   // SSA rename
  }
  // tile row-max: fmax triples -> v_max3_f32 fusion
  float t[11];
#pragma unroll
  for (int i = 0; i < 10; ++i)
    t[i] = fmaxf(fmaxf(PV(3 * i), PV(3 * i + 1)), PV(3 * i + 2));
  t[10] = fmaxf(PV(30), PV(31));
  const float u0 = fmaxf(fmaxf(t[0], t[1]), t[2]);
  const float u1 = fmaxf(fmaxf(t[3], t[4]), t[5]);
  const float u2 = fmaxf(fmaxf(t[6], t[7]), t[8]);
  const float u3 = fmaxf(t[9], t[10]);
  float mt = fmaxf(fmaxf(u0, u1), fmaxf(u2, u3));
  mt = fmaxf(mt, __shfl_xor(mt, 32));
  // T13: rescale only when the running max grew by > 8 (exp2 domain) in any lane
  if (!__all(mt - m2 <= 8.f)) {
    const float mnew = fmaxf(m2, mt);
    const float alpha = __builtin_amdgcn_exp2f(m2 - mnew);
    m2 = mnew;
    lsum *= alpha;
#pragma unroll
    for (int e = 0; e < 16; ++e) { oacc[0][e] *= alpha; oacc[1][e] *= alpha; }
  }
  const f32x2 mm = {m2, m2};
#pragma unroll
  for (int j = 0; j < 16; ++j) pp[j] -= mm;                    // v_pk_add_f32 (neg)
#pragma unroll
  for (int j = 0; j < 16; ++j) {
    pp[j][0] = __builtin_amdgcn_exp2f(pp[j][0]);
    pp[j][1] = __builtin_amdgcn_exp2f(pp[j][1]);
  }
  // packed sum tree: 15 pk_add + 1 scalar + 1 shfl
  f32x2 sa[8];
#pragma unroll
  for (int j = 0; j < 8; ++j) sa[j] = pp[j] + pp[j + 8];
  f32x2 sb[4];
#pragma unroll
  for (int j = 0; j < 4; ++j) sb[j] = sa[j] + sa[j + 4];
  f32x2 sc0 = sb[0] + sb[2], sc1 = sb[1] + sb[3];
  f32x2 sd = sc0 + sc1;
  float ssum = sd[0] + sd[1];
  ssum += __shfl_xor(ssum, 32);
  lsum += ssum;

  // P^T fragments via cvt_pk + permlane32_swap; O^T += V^T . P^T
  __builtin_amdgcn_s_setprio(1);
#pragma unroll
  for (int kb = 0; kb < 4; ++kb) {
    const int pb = (kb >> 1) * 16 + (kb & 1) * 8;
    u32 x = cvtpk(PV(pb + 0), PV(pb + 1));
    u32 y = cvtpk(PV(pb + 4), PV(pb + 5));
    asm volatile("v_permlane32_swap_b32 %0, %1" : "+v"(x), "+v"(y));
    u32 zz = cvtpk(PV(pb + 2), PV(pb + 3));
    u32 w = cvtpk(PV(pb + 6), PV(pb + 7));
    asm volatile("v_permlane32_swap_b32 %0, %1" : "+v"(zz), "+v"(w));
    union { u32 u[4]; short8 s; } bf;
    bf.u[0] = x; bf.u[1] = zz; bf.u[2] = y; bf.u[3] = w;
#pragma unroll
    for (int db = 0; db < 2; ++db)
      oacc[db] = __builtin_amdgcn_mfma_f32_32x32x16_bf16(vf[kb * 2 + db], bf.s, oacc[db], 0, 0, 0);
  }
  __builtin_amdgcn_s_setprio(0);
}

// ---- flash attention: 4 waves/block; wave pairs (qgrp, half): same 32 q-rows,
// half the KV range each. One-shot LDS combine per pair. XCD-swizzled.
// K reg ping-pong. VGPR discipline: must stay <= 128 (occupancy halves above —
// R10: 164 VGPR -> 77 µs). launch_bounds min-waves forces caps (R3/R8 spills):
// keep (256,2) which allows ~100-128.
__global__ __launch_bounds__(256, 2) void attn_kernel(
    const u16* __restrict__ qh, const u16* __restrict__ kh, const u16* __restrict__ vF,
    const float* __restrict__ mask, const u32* __restrict__ mflag, u16* __restrict__ O) {
  __shared__ float red[2][2][2][32];   // [qgrp][half][{m,l}][lq]
  __shared__ float osum[2][32][68];    // [qgrp][lq][d] pad 64->68
  const int wave = threadIdx.x >> 6, lane = threadIdx.x & 63;
  const int qgrp = wave >> 1, half = wave & 1;
  const int bid = blockIdx.x;
  const int vid = (bid & 7) * 128 + (bid >> 3);   // 1024 blocks, bijective
  const int bh = vid >> 5;
  const int q0 = (vid & 31) * 64 + qgrp * 32;
  const int lq = lane & 31;
  const int hi = lane >> 5;
  const u16* qp = qh + (size_t)bh * SEQ * DHD;
  const u16* kp = kh + (size_t)bh * SEQ * DHD;
  const u16* vp = vF + (size_t)bh * SEQ * DHD;
  const float* mrow = mask + (size_t)(q0 + lq) * SEQ;
  const u32 has_mask = *mflag;

  short8 qf[4];
#pragma unroll
  for (int d = 0; d < 4; ++d)
    qf[d] = *reinterpret_cast<const short8*>(&qp[(size_t)(q0 + lq) * DHD + d * 16 + hi * 8]);

  f32x16 oacc[2];
#pragma unroll
  for (int e = 0; e < 16; ++e) { oacc[0][e] = 0.f; oacc[1][e] = 0.f; }
  float m2 = -INFINITY, lsum = 0.f;

  const int kvb = half * (SEQ / 2);
  short8 ka[8], kb2[8];
  load_ktile(kp, kvb, lane, ka);
  for (int it = 0; it < 16; it += 2) {
    const int kv0 = kvb + (it << 6);
    load_ktile(kp, kv0 + 64, lane, kb2);
    attn_tile(ka, vp, mrow, has_mask, kv0, lane, hi, qf, oacc, m2, lsum);
    load_ktile(kp, (it == 14) ? kvb : kv0 + 128, lane, ka);
    attn_tile(kb2, vp, mrow, has_mask, kv0 + 64, lane, hi, qf, oacc, m2, lsum);
  }

  // ---- pairwise combine (half 0 + half 1) ----
  if (hi == 0) { red[qgrp][half][0][lq] = m2; red[qgrp][half][1][lq] = lsum; }
  __syncthreads();
  const float Mfin = fmaxf(red[qgrp][0][0][lq], red[qgrp][1][0][lq]);
  const float beta = __builtin_amdgcn_exp2f(m2 - Mfin);
  const float mo = red[qgrp][half ^ 1][0][lq];
  const float lo = red[qgrp][half ^ 1][1][lq];
  const float ltot = lsum * beta + lo * __builtin_amdgcn_exp2f(mo - Mfin);
#pragma unroll
  for (int e = 0; e < 16; ++e) { oacc[0][e] *= beta; oacc[1][e] *= beta; }
  if (half == 0) {
#pragma unroll
    for (int db = 0; db < 2; ++db)
#pragma unroll
      for (int g = 0; g < 4; ++g) {
        f32x4 v = {oacc[db][g * 4], oacc[db][g * 4 + 1], oacc[db][g * 4 + 2], oacc[db][g * 4 + 3]};
        *reinterpret_cast<f32x4*>(&osum[qgrp][lq][db * 32 + g * 8 + hi * 4]) = v;
      }
  }
  __syncthreads();
  if (half == 1) {
    const int b = bh >> 4, h = bh & 15;
    const float inv = 1.0f / ltot;
    u16* orow = O + ((size_t)(b * SEQ + q0 + lq) * NH + h) * DHD;
#pragma unroll
    for (int db = 0; db < 2; ++db)
#pragma unroll
      for (int g = 0; g < 4; ++g) {
        f32x4 s = *reinterpret_cast<const f32x4*>(&osum[qgrp][lq][db * 32 + g * 8 + hi * 4]);
        union { u32 u[2]; unsigned long long ll; } pk;
        pk.u[0] = cvtpk((s[0] + oacc[db][g * 4 + 0]) * inv, (s[1] + oacc[db][g * 4 + 1]) * inv);
        pk.u[1] = cvtpk((s[2] + oacc[db][g * 4 + 2]) * inv, (s[3] + oacc[db][g * 4 + 3]) * inv);
        *reinterpret_cast<unsigned long long*>(&orow[db * 32 + g * 8 + hi * 4]) = pk.ll;
      }
  }
}

// ---- output projection: d_out = O @ Wo^T + bo (fp32 out), m97 structure
__global__ __launch_bounds__(256) void out_proj_kernel(
    const u16* __restrict__ O, const u16* __restrict__ WoB, const float* __restrict__ bo,
    float* __restrict__ out) {
  __shared__ u16 As[128 * 32];
  __shared__ u16 Bs[128 * 32];
  const int rr = blockIdx.x;
  const int slot = rr >> 3;
  const int y = (rr & 7) + 8 * (slot & 3);
  const int x = slot >> 2;
  const int m0 = y * 128, n0 = x * 128;
  f32x4 acc[4][4];
  gemm128_bf16(O, WoB, m0, n0, As, Bs, acc);

  const int lane = threadIdx.x & 63;
  const int wr = (threadIdx.x >> 7) & 1, wc = (threadIdx.x >> 6) & 1;
  const int rbase = m0 + wr * 64 + ((lane >> 4) << 2);
  const int cbase = n0 + wc * 64 + (lane & 15);
#pragma unroll
  for (int n = 0; n < 4; ++n) {
    const int col = cbase + n * 16;
    const float bvv = bo[col];
#pragma unroll
    for (int m = 0; m < 4; ++m)
#pragma unroll
      for (int r = 0; r < 4; ++r) {
        const int row = rbase + m * 16 + r;
        out[(size_t)row * FD + col] = acc[m][n][r] + bvv;
      }
  }
}

extern "C" void kernel_launch(void* const* d_in, const int* in_sizes, int n_in,
                              void* d_out, int out_size, void* d_ws, size_t ws_size,
                              hipStream_t stream) {
  (void)in_sizes; (void)n_in; (void)out_size; (void)ws_size;
  const float* Q    = (const float*)d_in[0];
  const float* K    = (const float*)d_in[1];
  const float* V    = (const float*)d_in[2];
  const float* mask = (const float*)d_in[3];
  const float* Wq   = (const float*)d_in[4];
  const float* bq   = (const float*)d_in[5];
  const float* Wk   = (const float*)d_in[6];
  const float* bk   = (const float*)d_in[7];
  const float* Wv   = (const float*)d_in[8];
  const float* bv   = (const float*)d_in[9];
  const float* Wo   = (const float*)d_in[10];
  const float* bo   = (const float*)d_in[11];
  float* out = (float*)d_out;

  u16* ws = (u16*)d_ws;
  const size_t SZ = (size_t)4096 * 1024;   // B*S*F elements
  u16* qh  = ws;             // [B,H,S,DH] bf16 (q pre-scaled)
  u16* kh  = qh + SZ;        // K' fragment-major bf16
  u16* vF  = kh + SZ;        // V' fragment-major bf16
  u16* O   = vF + SZ;        // [B,S,H,DH] bf16
  u16* Wbf = O + SZ;         // [4][1024][1024] bf16 (Wq,Wk,Wv,Wo cast)
  u32* mflag = (u32*)(Wbf + 4 * (size_t)1024 * 1024);

  hipMemsetAsync(mflag, 0, 4, stream);
  prep_kernel<<<dim3(2048), 256, 0, stream>>>(Wq, Wk, Wv, Wo, Wbf);

  proj_qkv_kernel<<<dim3(2816), 256, 0, stream>>>(Q, K, V, Wbf, bq, bk, bv,
                                                  (const u32*)mask, mflag, qh, kh, vF);

  attn_kernel<<<dim3(1024), 256, 0, stream>>>(qh, kh, vF, mask, mflag, O);

  out_proj_kernel<<<dim3(256), 256, 0, stream>>>(O, Wbf + 3 * (size_t)1024 * 1024, bo, out);
}

// Round 16
// 136.946 us; speedup vs baseline: 1.1185x; 1.1185x over previous
//
#include <hip/hip_runtime.h>
#include <hip/hip_bf16.h>

typedef unsigned short u16;
typedef unsigned int u32;
typedef __attribute__((ext_vector_type(2))) float f32x2;
typedef __attribute__((ext_vector_type(4))) float f32x4;
typedef __attribute__((ext_vector_type(16))) float f32x16;
typedef __attribute__((ext_vector_type(8))) short short8;
typedef __attribute__((ext_vector_type(4))) u32 u32x4;

#define SEQ 2048
#define FD  1024
#define NH  16
#define DHD 64

// R16 = R14/R12 verbatim revert (last known-good: 137.5us, validated twice).
// R15's mixed-staging proj regressed 30->90us: putting a reg-staged
// load+cvt+ds_write chain on the staging path serializes the 2-barrier K-loop;
// global_load_lds's asynchrony is the load-bearing property of this structure.

__device__ __forceinline__ u16 f2bf(float f) {
  __hip_bfloat16 h = __float2bfloat16(f);
  return *reinterpret_cast<u16*>(&h);
}
__device__ __forceinline__ u32 pack2bf(float lo, float hi) {
  return (u32)f2bf(lo) | ((u32)f2bf(hi) << 16);
}
// hardware packed f32->bf16 (RNE), 1 instr for 2 values (T12 recipe)
__device__ __forceinline__ u32 cvtpk(float lo, float hi) {
  u32 r;
  asm("v_cvt_pk_bf16_f32 %0, %1, %2" : "=v"(r) : "v"(lo), "v"(hi));
  return r;
}

// async global->LDS, 16B per lane. LDS dest = wave-uniform base + lane*16.
#define GLOAD_LDS16(gp, lp)                                        \
  __builtin_amdgcn_global_load_lds(                                \
      (const __attribute__((address_space(1))) unsigned int*)(gp), \
      (__attribute__((address_space(3))) unsigned int*)(lp), 16, 0, 0)

// ---- prep: fp32->bf16 cast of Q,K,V (->Abf[3]) and Wq,Wk,Wv,Wo (->Wbf[4]).
// (mask zero-check lives in proj_qkv launch to hide its 64MB read under compute)
__global__ __launch_bounds__(256) void prep_kernel(
    const float* __restrict__ Q, const float* __restrict__ K, const float* __restrict__ V,
    const float* __restrict__ Wq, const float* __restrict__ Wk, const float* __restrict__ Wv,
    const float* __restrict__ Wo,
    u16* __restrict__ Abf, u16* __restrict__ Wbf) {
  const size_t i = ((size_t)blockIdx.x * 256 + threadIdx.x) * 8;
  const float* src;
  u16* dst;
  if (i < 12582912) {           // Q,K,V: 3 x 2^22
    const int s = (int)(i >> 22);
    const size_t off = i & 0x3FFFFF;
    src = (s == 0 ? Q : s == 1 ? K : V) + off;
    dst = Abf + i;
  } else {                      // W: 4 x 2^20
    const size_t j = i - 12582912;
    const int w = (int)(j >> 20);
    const size_t off = j & 0xFFFFF;
    src = (w == 0 ? Wq : w == 1 ? Wk : w == 2 ? Wv : Wo) + off;
    dst = Wbf + j;
  }
  f32x4 a = *reinterpret_cast<const f32x4*>(src);
  f32x4 b = *reinterpret_cast<const f32x4*>(src + 4);
  union { u32 u[4]; short8 s; } pk;
  pk.u[0] = pack2bf(a[0], a[1]); pk.u[1] = pack2bf(a[2], a[3]);
  pk.u[2] = pack2bf(b[0], b[1]); pk.u[3] = pack2bf(b[2], b[3]);
  *reinterpret_cast<short8*>(dst) = pk.s;
}

// ---- m97-structure 128x128 GEMM body: C = A[M,1024] * W[N,1024]^T, both bf16,
// BK=32, global_load_lds(16) staging, 16x16x32 MFMA, fp32 acc[4][4].
__device__ __forceinline__ void gemm128_bf16(const u16* __restrict__ A, const u16* __restrict__ W,
                                             int m0, int n0, u16* As, u16* Bs,
                                             f32x4 (&acc)[4][4]) {
  const int tid = threadIdx.x, lane = tid & 63, wv = tid >> 6;
  const int wr = (tid >> 7) & 1, wc = (tid >> 6) & 1;
  const int lr = lane & 15, lk = (lane >> 4) << 3;
  const int srow = lane >> 2;          // wave-local staging row (0..15)
  const int scol = (lane & 3) << 3;    // staging col (0,8,16,24)
#pragma unroll
  for (int m = 0; m < 4; ++m)
#pragma unroll
    for (int n = 0; n < 4; ++n) acc[m][n] = {0.f, 0.f, 0.f, 0.f};

  for (int k0 = 0; k0 < FD; k0 += 32) {
    __syncthreads();   // previous iteration's ds_reads done (lgkm drain)
#pragma unroll
    for (int c = 0; c < 2; ++c) {
      GLOAD_LDS16(&A[(size_t)(m0 + c * 64 + wv * 16 + srow) * FD + k0 + scol],
                  &As[(c * 64 + wv * 16) * 32]);
      GLOAD_LDS16(&W[(size_t)(n0 + c * 64 + wv * 16 + srow) * FD + k0 + scol],
                  &Bs[(c * 64 + wv * 16) * 32]);
    }
    __syncthreads();   // vmcnt(0) drain: staged tile visible
    short8 a[4], b[4];
#pragma unroll
    for (int m = 0; m < 4; ++m)
      a[m] = *reinterpret_cast<const short8*>(&As[(wr * 64 + m * 16 + lr) * 32 + lk]);
#pragma unroll
    for (int n = 0; n < 4; ++n)
      b[n] = *reinterpret_cast<const short8*>(&Bs[(wc * 64 + n * 16 + lr) * 32 + lk]);
#pragma unroll
    for (int m = 0; m < 4; ++m)
#pragma unroll
      for (int n = 0; n < 4; ++n)
        acc[m][n] = __builtin_amdgcn_mfma_f32_16x16x32_bf16(a[m], b[n], acc[m][n], 0, 0, 0);
  }
}

// ---- fused QKV projection (bf16 in) + mask zero-check blocks (bid >= 768).
// q -> [B,H,S,DH] (pre-scaled by 0.125*log2e); k,v -> fragment-major K'/V'.
__global__ __launch_bounds__(256) void proj_qkv_kernel(
    const u16* __restrict__ Abf, const u16* __restrict__ Wbf,
    const float* __restrict__ bq, const float* __restrict__ bk, const float* __restrict__ bv,
    const u32* __restrict__ mask_u32, u32* __restrict__ mflag,
    u16* __restrict__ qh, u16* __restrict__ kh, u16* __restrict__ vF) {
  __shared__ u16 As[128 * 32];
  __shared__ u16 Bs[128 * 32];
  const int bid = blockIdx.x;
  if (bid >= 768) {   // mask zero-check: 2048 blocks x 2048 f32, overlapped with GEMM
    const size_t cb = (size_t)(bid - 768) * 2048 + ((size_t)threadIdx.x << 3);
    u32x4 a = *reinterpret_cast<const u32x4*>(&mask_u32[cb]);
    u32x4 b = *reinterpret_cast<const u32x4*>(&mask_u32[cb + 4]);
    u32 o = a[0] | a[1] | a[2] | a[3] | b[0] | b[1] | b[2] | b[3];
    if (__ballot(o != 0) != 0ull && (threadIdx.x & 63) == 0) atomicOr(mflag, 1u);
    return;
  }
  const int which = bid >> 8;
  const int rr = bid & 255;
  const int slot = rr >> 3;
  const int y = (rr & 7) + 8 * (slot & 3);  // XCD = rr%8 owns 4 m-bands, all n-tiles
  const int x = slot >> 2;
  const int m0 = y * 128, n0 = x * 128;
  const u16* A = Abf + ((size_t)which << 22);
  const u16* W = Wbf + ((size_t)which << 20);
  const float* bias = (which == 0) ? bq : (which == 1) ? bk : bv;
  const float qscale = 0.18033688011112042f;  // (1/8) * log2(e)

  f32x4 acc[4][4];
  gemm128_bf16(A, W, m0, n0, As, Bs, acc);

  u16* out = (which == 0) ? qh : (which == 1) ? kh : vF;
  const int lane = threadIdx.x & 63;
  const int wr = (threadIdx.x >> 7) & 1, wc = (threadIdx.x >> 6) & 1;
  const int rbase = m0 + wr * 64 + ((lane >> 4) << 2);
  const int cbase = n0 + wc * 64 + (lane & 15);
#pragma unroll
  for (int n = 0; n < 4; ++n) {
    const int col = cbase + n * 16;
    const float bvv = bias[col];
    const int h = col >> 6, dh = col & 63;
#pragma unroll
    for (int m = 0; m < 4; ++m) {
#pragma unroll
      for (int r = 0; r < 4; ++r) {
        const int row = rbase + m * 16 + r;
        const int b = row >> 11, s = row & 2047;
        float v = acc[m][n][r] + bvv;
        if (which == 0) v *= qscale;
        const size_t bhbase = (size_t)(b * 16 + h) * SEQ * DHD;
        size_t idx;
        if (which == 0) {
          idx = bhbase + (size_t)s * 64 + dh;                                   // [B,H,S,DH]
        } else if (which == 1) {
          idx = bhbase + ((size_t)(((s >> 5) * 4 + (dh >> 4)) * 64
                          + ((dh >> 3) & 1) * 32 + (s & 31)) << 3) + (dh & 7);  // K' frag
        } else {
          idx = bhbase + ((size_t)(((s >> 4) * 2 + (dh >> 5)) * 64
                          + ((s >> 3) & 1) * 32 + (dh & 31)) << 3) + (s & 7);   // V' frag
        }
        out[idx] = f2bf(v);
      }
    }
  }
}

__device__ __forceinline__ void load_ktile(const u16* __restrict__ kp, int kv0, int lane,
                                           short8 (&kf)[8]) {
#pragma unroll
  for (int h2 = 0; h2 < 2; ++h2)
#pragma unroll
    for (int d = 0; d < 4; ++d)
      kf[h2 * 4 + d] = *reinterpret_cast<const short8*>(
          &kp[((size_t)((((kv0 >> 5) + h2) * 4 + d) * 64 + lane)) << 3]);
}

#define PV(i) pp[(i) >> 1][(i) & 1]

// one 32q x 64kv tile. p held as f32x2 pairs (all-static idx) so clang emits
// v_pk_{add,fma}_f32 for sum tree / subtract / mask-FMA (halves those VALU ops).
// T13 defer-max (THR=8), T12 cvt_pk pack, T17 max3 triples, T5 setprio.
__device__ __forceinline__ void attn_tile(
    const short8 (&kf)[8], const u16* __restrict__ vp, const float* __restrict__ mrow,
    u32 has_mask, int kv0, int lane, int hi, const short8 (&qf)[4],
    f32x16 (&oacc)[2], float& m2, float& lsum) {
  const float L2E = 1.44269504088896340736f;
  short8 vf[8];
#pragma unroll
  for (int kb = 0; kb < 4; ++kb)
#pragma unroll
    for (int db = 0; db < 2; ++db)
      vf[kb * 2 + db] = *reinterpret_cast<const short8*>(
          &vp[((size_t)((((kv0 >> 4) + kb) * 2 + db) * 64 + lane)) << 3]);

  f32x16 st[2];
  __builtin_amdgcn_s_setprio(1);
#pragma unroll
  for (int h2 = 0; h2 < 2; ++h2) {
    f32x16 z;
#pragma unroll
    for (int e = 0; e < 16; ++e) z[e] = 0.f;
#pragma unroll
    for (int d = 0; d < 4; ++d)
      z = __builtin_amdgcn_mfma_f32_32x32x16_bf16(kf[h2 * 4 + d], qf[d], z, 0, 0, 0);
    st[h2] = z;
  }
  __builtin_amdgcn_s_setprio(0);
  f32x2 pp[16];
  if (__builtin_expect(has_mask != 0, 0)) {
#pragma unroll
    for (int h2 = 0; h2 < 2; ++h2)
#pragma unroll
      for (int g = 0; g < 4; ++g) {
        f32x4 mv = *reinterpret_cast<const f32x4*>(&mrow[kv0 + h2 * 32 + g * 8 + hi * 4]);
        const int pb = h2 * 8 + g * 2;
        f32x2 m0 = {mv[0], mv[1]}, m1 = {mv[2], mv[3]};
        f32x2 s0 = {st[h2][g * 4 + 0], st[h2][g * 4 + 1]};
        f32x2 s1 = {st[h2][g * 4 + 2], st[h2][g * 4 + 3]};
        pp[pb]     = m0 * L2E + s0;   // v_pk_fma_f32
        pp[pb + 1] = m1 * L2E + s1;
      }
  } else {
#pragma unroll
    for (int j = 0; j < 16; ++j)
      pp[j] = {st[j >> 3][(2 * j) & 15], st[j >> 3][(2 * j + 1) & 15]};   // SSA rename
  }
  // tile row-max: fmax triples -> v_max3_f32 fusion
  float t[11];
#pragma unroll
  for (int i = 0; i < 10; ++i)
    t[i] = fmaxf(fmaxf(PV(3 * i), PV(3 * i + 1)), PV(3 * i + 2));
  t[10] = fmaxf(PV(30), PV(31));
  const float u0 = fmaxf(fmaxf(t[0], t[1]), t[2]);
  const float u1 = fmaxf(fmaxf(t[3], t[4]), t[5]);
  const float u2 = fmaxf(fmaxf(t[6], t[7]), t[8]);
  const float u3 = fmaxf(t[9], t[10]);
  float mt = fmaxf(fmaxf(u0, u1), fmaxf(u2, u3));
  mt = fmaxf(mt, __shfl_xor(mt, 32));
  // T13: rescale only when the running max grew by > 8 (exp2 domain) in any lane
  if (!__all(mt - m2 <= 8.f)) {
    const float mnew = fmaxf(m2, mt);
    const float alpha = __builtin_amdgcn_exp2f(m2 - mnew);
    m2 = mnew;
    lsum *= alpha;
#pragma unroll
    for (int e = 0; e < 16; ++e) { oacc[0][e] *= alpha; oacc[1][e] *= alpha; }
  }
  const f32x2 mm = {m2, m2};
#pragma unroll
  for (int j = 0; j < 16; ++j) pp[j] -= mm;                    // v_pk_add_f32 (neg)
#pragma unroll
  for (int j = 0; j < 16; ++j) {
    pp[j][0] = __builtin_amdgcn_exp2f(pp[j][0]);
    pp[j][1] = __builtin_amdgcn_exp2f(pp[j][1]);
  }
  // packed sum tree: 15 pk_add + 1 scalar + 1 shfl
  f32x2 sa[8];
#pragma unroll
  for (int j = 0; j < 8; ++j) sa[j] = pp[j] + pp[j + 8];
  f32x2 sb[4];
#pragma unroll
  for (int j = 0; j < 4; ++j) sb[j] = sa[j] + sa[j + 4];
  f32x2 sc0 = sb[0] + sb[2], sc1 = sb[1] + sb[3];
  f32x2 sd = sc0 + sc1;
  float ssum = sd[0] + sd[1];
  ssum += __shfl_xor(ssum, 32);
  lsum += ssum;

  // P^T fragments via cvt_pk + permlane32_swap; O^T += V^T . P^T
  __builtin_amdgcn_s_setprio(1);
#pragma unroll
  for (int kb = 0; kb < 4; ++kb) {
    const int pb = (kb >> 1) * 16 + (kb & 1) * 8;
    u32 x = cvtpk(PV(pb + 0), PV(pb + 1));
    u32 y = cvtpk(PV(pb + 4), PV(pb + 5));
    asm volatile("v_permlane32_swap_b32 %0, %1" : "+v"(x), "+v"(y));
    u32 zz = cvtpk(PV(pb + 2), PV(pb + 3));
    u32 w = cvtpk(PV(pb + 6), PV(pb + 7));
    asm volatile("v_permlane32_swap_b32 %0, %1" : "+v"(zz), "+v"(w));
    union { u32 u[4]; short8 s; } bf;
    bf.u[0] = x; bf.u[1] = zz; bf.u[2] = y; bf.u[3] = w;
#pragma unroll
    for (int db = 0; db < 2; ++db)
      oacc[db] = __builtin_amdgcn_mfma_f32_32x32x16_bf16(vf[kb * 2 + db], bf.s, oacc[db], 0, 0, 0);
  }
  __builtin_amdgcn_s_setprio(0);
}

// ---- flash attention: 4 waves/block; wave pairs (qgrp, half): same 32 q-rows,
// half the KV range each. One-shot LDS combine per pair. XCD-swizzled.
// K reg ping-pong. VGPR discipline: must stay <= 128 (occupancy halves above —
// R10: 164 VGPR -> 77 µs). launch_bounds min-waves forces caps (R3/R8 spills):
// keep (256,2) which allows ~100-128.
__global__ __launch_bounds__(256, 2) void attn_kernel(
    const u16* __restrict__ qh, const u16* __restrict__ kh, const u16* __restrict__ vF,
    const float* __restrict__ mask, const u32* __restrict__ mflag, u16* __restrict__ O) {
  __shared__ float red[2][2][2][32];   // [qgrp][half][{m,l}][lq]
  __shared__ float osum[2][32][68];    // [qgrp][lq][d] pad 64->68
  const int wave = threadIdx.x >> 6, lane = threadIdx.x & 63;
  const int qgrp = wave >> 1, half = wave & 1;
  const int bid = blockIdx.x;
  const int vid = (bid & 7) * 128 + (bid >> 3);   // 1024 blocks, bijective
  const int bh = vid >> 5;
  const int q0 = (vid & 31) * 64 + qgrp * 32;
  const int lq = lane & 31;
  const int hi = lane >> 5;
  const u16* qp = qh + (size_t)bh * SEQ * DHD;
  const u16* kp = kh + (size_t)bh * SEQ * DHD;
  const u16* vp = vF + (size_t)bh * SEQ * DHD;
  const float* mrow = mask + (size_t)(q0 + lq) * SEQ;
  const u32 has_mask = *mflag;

  short8 qf[4];
#pragma unroll
  for (int d = 0; d < 4; ++d)
    qf[d] = *reinterpret_cast<const short8*>(&qp[(size_t)(q0 + lq) * DHD + d * 16 + hi * 8]);

  f32x16 oacc[2];
#pragma unroll
  for (int e = 0; e < 16; ++e) { oacc[0][e] = 0.f; oacc[1][e] = 0.f; }
  float m2 = -INFINITY, lsum = 0.f;

  const int kvb = half * (SEQ / 2);
  short8 ka[8], kb2[8];
  load_ktile(kp, kvb, lane, ka);
  for (int it = 0; it < 16; it += 2) {
    const int kv0 = kvb + (it << 6);
    load_ktile(kp, kv0 + 64, lane, kb2);
    attn_tile(ka, vp, mrow, has_mask, kv0, lane, hi, qf, oacc, m2, lsum);
    load_ktile(kp, (it == 14) ? kvb : kv0 + 128, lane, ka);
    attn_tile(kb2, vp, mrow, has_mask, kv0 + 64, lane, hi, qf, oacc, m2, lsum);
  }

  // ---- pairwise combine (half 0 + half 1) ----
  if (hi == 0) { red[qgrp][half][0][lq] = m2; red[qgrp][half][1][lq] = lsum; }
  __syncthreads();
  const float Mfin = fmaxf(red[qgrp][0][0][lq], red[qgrp][1][0][lq]);
  const float beta = __builtin_amdgcn_exp2f(m2 - Mfin);
  const float mo = red[qgrp][half ^ 1][0][lq];
  const float lo = red[qgrp][half ^ 1][1][lq];
  const float ltot = lsum * beta + lo * __builtin_amdgcn_exp2f(mo - Mfin);
#pragma unroll
  for (int e = 0; e < 16; ++e) { oacc[0][e] *= beta; oacc[1][e] *= beta; }
  if (half == 0) {
#pragma unroll
    for (int db = 0; db < 2; ++db)
#pragma unroll
      for (int g = 0; g < 4; ++g) {
        f32x4 v = {oacc[db][g * 4], oacc[db][g * 4 + 1], oacc[db][g * 4 + 2], oacc[db][g * 4 + 3]};
        *reinterpret_cast<f32x4*>(&osum[qgrp][lq][db * 32 + g * 8 + hi * 4]) = v;
      }
  }
  __syncthreads();
  if (half == 1) {
    const int b = bh >> 4, h = bh & 15;
    const float inv = 1.0f / ltot;
    u16* orow = O + ((size_t)(b * SEQ + q0 + lq) * NH + h) * DHD;
#pragma unroll
    for (int db = 0; db < 2; ++db)
#pragma unroll
      for (int g = 0; g < 4; ++g) {
        f32x4 s = *reinterpret_cast<const f32x4*>(&osum[qgrp][lq][db * 32 + g * 8 + hi * 4]);
        union { u32 u[2]; unsigned long long ll; } pk;
        pk.u[0] = cvtpk((s[0] + oacc[db][g * 4 + 0]) * inv, (s[1] + oacc[db][g * 4 + 1]) * inv);
        pk.u[1] = cvtpk((s[2] + oacc[db][g * 4 + 2]) * inv, (s[3] + oacc[db][g * 4 + 3]) * inv);
        *reinterpret_cast<unsigned long long*>(&orow[db * 32 + g * 8 + hi * 4]) = pk.ll;
      }
  }
}

// ---- output projection: d_out = O @ Wo^T + bo (fp32 out), m97 structure
__global__ __launch_bounds__(256) void out_proj_kernel(
    const u16* __restrict__ O, const u16* __restrict__ WoB, const float* __restrict__ bo,
    float* __restrict__ out) {
  __shared__ u16 As[128 * 32];
  __shared__ u16 Bs[128 * 32];
  const int rr = blockIdx.x;
  const int slot = rr >> 3;
  const int y = (rr & 7) + 8 * (slot & 3);
  const int x = slot >> 2;
  const int m0 = y * 128, n0 = x * 128;
  f32x4 acc[4][4];
  gemm128_bf16(O, WoB, m0, n0, As, Bs, acc);

  const int lane = threadIdx.x & 63;
  const int wr = (threadIdx.x >> 7) & 1, wc = (threadIdx.x >> 6) & 1;
  const int rbase = m0 + wr * 64 + ((lane >> 4) << 2);
  const int cbase = n0 + wc * 64 + (lane & 15);
#pragma unroll
  for (int n = 0; n < 4; ++n) {
    const int col = cbase + n * 16;
    const float bvv = bo[col];
#pragma unroll
    for (int m = 0; m < 4; ++m)
#pragma unroll
      for (int r = 0; r < 4; ++r) {
        const int row = rbase + m * 16 + r;
        out[(size_t)row * FD + col] = acc[m][n][r] + bvv;
      }
  }
}

extern "C" void kernel_launch(void* const* d_in, const int* in_sizes, int n_in,
                              void* d_out, int out_size, void* d_ws, size_t ws_size,
                              hipStream_t stream) {
  (void)in_sizes; (void)n_in; (void)out_size; (void)ws_size;
  const float* Q    = (const float*)d_in[0];
  const float* K    = (const float*)d_in[1];
  const float* V    = (const float*)d_in[2];
  const float* mask = (const float*)d_in[3];
  const float* Wq   = (const float*)d_in[4];
  const float* bq   = (const float*)d_in[5];
  const float* Wk   = (const float*)d_in[6];
  const float* bk   = (const float*)d_in[7];
  const float* Wv   = (const float*)d_in[8];
  const float* bv   = (const float*)d_in[9];
  const float* Wo   = (const float*)d_in[10];
  const float* bo   = (const float*)d_in[11];
  float* out = (float*)d_out;

  u16* ws = (u16*)d_ws;
  const size_t SZ = (size_t)4096 * 1024;   // B*S*F elements
  u16* qh  = ws;             // [B,H,S,DH] bf16 (q pre-scaled)
  u16* kh  = qh + SZ;        // K' fragment-major bf16
  u16* vF  = kh + SZ;        // V' fragment-major bf16
  u16* O   = vF + SZ;        // [B,S,H,DH] bf16
  u16* Abf = O + SZ;         // [3][4096][1024] bf16 (Q,K,V inputs cast)
  u16* Wbf = Abf + 3 * SZ;   // [4][1024][1024] bf16 (Wq,Wk,Wv,Wo cast)
  u32* mflag = (u32*)(Wbf + 4 * (size_t)1024 * 1024);

  hipMemsetAsync(mflag, 0, 4, stream);
  prep_kernel<<<dim3(8192), 256, 0, stream>>>(Q, K, V, Wq, Wk, Wv, Wo, Abf, Wbf);

  proj_qkv_kernel<<<dim3(2816), 256, 0, stream>>>(Abf, Wbf, bq, bk, bv,
                                                  (const u32*)mask, mflag, qh, kh, vF);

  attn_kernel<<<dim3(1024), 256, 0, stream>>>(qh, kh, vF, mask, mflag, O);

  out_proj_kernel<<<dim3(256), 256, 0, stream>>>(O, Wbf + 3 * (size_t)1024 * 1024, bo, out);
}